// Round 4
// baseline (827.282 us; speedup 1.0000x reference)
//
#include <hip/hip_runtime.h>
#include <hip/hip_bf16.h>
#include <stdint.h>
#include <stddef.h>

typedef __hip_bfloat16 bf16;
typedef __attribute__((ext_vector_type(8))) short short8;
typedef __attribute__((ext_vector_type(4))) float f32x4;

#define GLDS16(g, l) __builtin_amdgcn_global_load_lds( \
    (const __attribute__((address_space(1))) void*)(g), \
    (__attribute__((address_space(3))) void*)(l), 16, 0, 0)

__device__ __forceinline__ float bf2f(bf16 x) { return __bfloat162float(x); }
__device__ __forceinline__ bf16  f2bf(float x) { return __float2bfloat16(x); }

constexpr int CAP = 4096;

// ================= merged weight convert+transpose (all weights, one dispatch) ===============
struct WJob { const float* src; bf16* dhi; bf16* dlo; int K, N, start; };
struct WJobs { WJob j[7]; };

__global__ void wconv_all(WJobs jobs) {
  __shared__ float tile[32][33];
  const int bid = blockIdx.x;
  int ji = 0;
#pragma unroll
  for (int t = 1; t < 7; ++t) if (bid >= jobs.j[t].start) ji = t;
  const WJob J = jobs.j[ji];
  const int K = J.K, N = J.N;
  const int nx = N >> 5, tps = nx * (K >> 5);
  const int local = bid - J.start;
  const int z = local / tps, rem = local % tps;
  const int n0 = (rem % nx) * 32, k0 = (rem / nx) * 32;
  const size_t zoff = (size_t)z * K * N;
  const float* s = J.src + zoff;
  const int tx = threadIdx.x & 31, ty = threadIdx.x >> 5;
#pragma unroll
  for (int i = 0; i < 32; i += 8)
    tile[ty + i][tx] = s[(size_t)(k0 + ty + i) * N + (n0 + tx)];
  __syncthreads();
  const bool split = (J.dlo != nullptr);
#pragma unroll
  for (int i = 0; i < 32; i += 8) {
    const float v = tile[tx][ty + i];
    const size_t o = zoff + (size_t)(n0 + ty + i) * K + (k0 + tx);
    const bf16 h = f2bf(v);
    J.dhi[o] = h;
    if (split) J.dlo[o] = f2bf(v - bf2f(h));
  }
}

// ================= elementwise f32 -> bf16 hi/lo split =================
__global__ void splitv(const float* __restrict__ x, bf16* __restrict__ hi,
                       bf16* __restrict__ lo, int n4) {
  const int i = blockIdx.x * 256 + threadIdx.x;
  if (i >= n4) return;
  const float4 v = ((const float4*)x)[i];
  const float f[4] = {v.x, v.y, v.z, v.w};
#pragma unroll
  for (int j = 0; j < 4; ++j) {
    const bf16 h = f2bf(f[j]);
    hi[i * 4 + j] = h;
    lo[i * 4 + j] = f2bf(f[j] - bf2f(h));
  }
}

// ================= core 128x128 tile GEMM body, BK=32 =================
// EPI: 0 relu -> (Ch,Cl)            1 +bias +Rh+Rl -> (Ch,Cl)
//      3 relu -> Ch                 4 +bias +Rb -> Ch
//      5 +bias +Rb(perm-gathered rows) -> Ch
//      6 raw f32 partial -> Cf (split-K, no bias)
template<int EPI, bool SPLIT, bool GATHER>
__device__ __forceinline__ void gemm_tile(
    const bf16* __restrict__ Ah, const bf16* __restrict__ Al,
    const bf16* __restrict__ Bh, const bf16* __restrict__ Bl,
    const float* __restrict__ bias,
    const bf16* __restrict__ Rb, const bf16* __restrict__ Rl2,
    float* __restrict__ Cf, bf16* __restrict__ Ch, bf16* __restrict__ Cl,
    const int* __restrict__ permz, int cE,
    int bx, int by, int N, int K, int lda, int kbase,
    bf16* As, bf16* Bs) {
  const int tid = threadIdx.x, lane = tid & 63, wave = tid >> 6;
  const int wr = wave >> 1, wc = wave & 1;
  const int fr = lane & 15, q = lane >> 4, fq = q << 2;

  int arow[2], brow[2];
#pragma unroll
  for (int i = 0; i < 2; ++i) {
    const int r = (i * 256 + tid) >> 2;
    const int slot = bx * 128 + r;
    arow[i] = GATHER ? ((slot < cE) ? permz[slot] : 0) : slot;
    brow[i] = by * 128 + r;
  }

  f32x4 acc[4][4];
#pragma unroll
  for (int m = 0; m < 4; ++m)
#pragma unroll
    for (int n = 0; n < 4; ++n) {
      acc[m][n][0] = 0.f; acc[m][n][1] = 0.f; acc[m][n][2] = 0.f; acc[m][n][3] = 0.f;
    }

  const int nk = K >> 5;
  for (int kt = 0; kt < nk; ++kt) {
    const int k0 = kbase + (kt << 5);
#pragma unroll
    for (int i = 0; i < 2; ++i) {
      const int ci = i * 256 + tid;
      const int r = ci >> 2, pch = ci & 3;
      const int c = pch ^ ((r >> 1) & 3);          // inverse-swizzled global chunk
      const size_t ga = (size_t)arow[i] * lda + k0 + c * 8;
      const size_t gb = (size_t)brow[i] * lda + k0 + c * 8;
      GLDS16(Ah + ga, As + ci * 8);
      GLDS16(Bh + gb, Bs + ci * 8);
      if (SPLIT) {
        GLDS16(Al + ga, As + 4096 + ci * 8);
        GLDS16(Bl + gb, Bs + 4096 + ci * 8);
      }
    }
    __syncthreads();

    auto LD = [&](const bf16* base, int r) -> short8 {
      const int c = q ^ ((r >> 1) & 3);            // swizzled fragment read
      return *(const short8*)(base + r * 32 + c * 8);
    };
    short8 a0[4], b0[4];
#pragma unroll
    for (int m = 0; m < 4; ++m) a0[m] = LD(As, wr * 64 + m * 16 + fr);
#pragma unroll
    for (int n = 0; n < 4; ++n) b0[n] = LD(Bs, wc * 64 + n * 16 + fr);
    if (SPLIT) {
      short8 a1[4], b1[4];
#pragma unroll
      for (int m = 0; m < 4; ++m) a1[m] = LD(As + 4096, wr * 64 + m * 16 + fr);
#pragma unroll
      for (int n = 0; n < 4; ++n) b1[n] = LD(Bs + 4096, wc * 64 + n * 16 + fr);
#pragma unroll
      for (int m = 0; m < 4; ++m)
#pragma unroll
        for (int n = 0; n < 4; ++n) {
          acc[m][n] = __builtin_amdgcn_mfma_f32_16x16x32_bf16(a1[m], b0[n], acc[m][n], 0, 0, 0);
          acc[m][n] = __builtin_amdgcn_mfma_f32_16x16x32_bf16(a0[m], b1[n], acc[m][n], 0, 0, 0);
        }
    }
#pragma unroll
    for (int m = 0; m < 4; ++m)
#pragma unroll
      for (int n = 0; n < 4; ++n)
        acc[m][n] = __builtin_amdgcn_mfma_f32_16x16x32_bf16(a0[m], b0[n], acc[m][n], 0, 0, 0);
    __syncthreads();
  }

#pragma unroll
  for (int n = 0; n < 4; ++n) {
    const int col = by * 128 + wc * 64 + n * 16 + fr;
    const float bv = (EPI == 6) ? 0.f : bias[col];
#pragma unroll
    for (int m = 0; m < 4; ++m) {
      const int row0 = bx * 128 + wr * 64 + m * 16 + fq;
#pragma unroll
      for (int r = 0; r < 4; ++r) {
        const int rowi = row0 + r;
        const size_t o = (size_t)rowi * N + col;
        float v = acc[m][n][r] + bv;
        if (EPI == 0 || EPI == 3) v = fmaxf(v, 0.f);
        if (EPI == 1) v += bf2f(Rb[o]) + bf2f(Rl2[o]);
        if (EPI == 4) v += bf2f(Rb[o]);
        if (EPI == 5) {
          const int rr = (rowi < cE) ? permz[rowi] : 0;
          v += bf2f(Rb[(size_t)rr * N + col]);
        }
        if (EPI == 6) {
          Cf[o] = v;
        } else {
          const bf16 h = f2bf(v);
          Ch[o] = h;
          if (EPI == 0 || EPI == 1) Cl[o] = f2bf(v - bf2f(h));
        }
      }
    }
  }
}

// ================= single GEMM (experts / split-K final) ===============
template<int EPI, bool SPLIT, bool GATHER, bool SPLITK>
__global__ __launch_bounds__(256, 3)
void gemm_bt(const bf16* __restrict__ Ah, const bf16* __restrict__ Al, size_t aSz,
             const bf16* __restrict__ Bh, const bf16* __restrict__ Bl, size_t bSz,
             const float* __restrict__ bias, size_t biasSz,
             const void* __restrict__ R, size_t rSz,
             float* __restrict__ Cf, bf16* __restrict__ Ch, bf16* __restrict__ Cl, size_t cSz,
             const int* __restrict__ perm, const int* __restrict__ cnt,
             int M, int N, int K, int lda) {
  __shared__ __align__(16) bf16 As[(SPLIT ? 2 : 1) * 4096];
  __shared__ __align__(16) bf16 Bs[(SPLIT ? 2 : 1) * 4096];
  const int gx = M >> 7, gy = N >> 7, nwg = gridDim.x, lid = blockIdx.x;
  const int wid = (lid & 7) * (nwg >> 3) + (lid >> 3);
  const int by = wid % gy, bx = (wid / gy) % gx, bz = wid / (gy * gx);

  int cE = 0x7fffffff;
  if (cnt) { cE = cnt[bz]; if (bx * 128 >= cE) return; }

  Ah += (size_t)bz * aSz;
  Bh += (size_t)bz * bSz;
  if (SPLIT) { Al += (size_t)bz * aSz; Bl += (size_t)bz * bSz; }
  if (bias) bias += (size_t)bz * biasSz;
  const bf16* Rb = (const bf16*)R;
  if (EPI == 4) Rb += (size_t)bz * rSz;
  if (EPI == 6) Cf += (size_t)bz * cSz; else Ch += (size_t)bz * cSz;
  const int* permz = perm ? (perm + (size_t)bz * CAP) : nullptr;
  const int kbase = SPLITK ? bz * K : 0;

  gemm_tile<EPI, SPLIT, GATHER>(Ah, Al, Bh, Bl, bias, Rb, nullptr, Cf, Ch, Cl,
                                permz, cE, bx, by, N, K, lda, kbase, As, Bs);
}

// ================= dual GEMM: z=0 split(enc), z=1 plain(value), z interleaved lowest bit ===============
template<int EPI0, int EPI1>
__global__ __launch_bounds__(256, 3)
void gemm_dual(const bf16* __restrict__ Ah, const bf16* __restrict__ Al,
               const bf16* __restrict__ B0h, const bf16* __restrict__ B0l,
               const float* __restrict__ bias0,
               const bf16* __restrict__ R0h, const bf16* __restrict__ R0l,
               bf16* __restrict__ C0h, bf16* __restrict__ C0l,
               const bf16* __restrict__ A1, const bf16* __restrict__ B1,
               const float* __restrict__ bias1, const bf16* __restrict__ R1,
               bf16* __restrict__ C1,
               int M, int N, int K) {
  __shared__ __align__(16) bf16 As[2 * 4096];
  __shared__ __align__(16) bf16 Bs[2 * 4096];
  const int gy = N >> 7, nwg = gridDim.x, lid = blockIdx.x;
  const int wid = (lid & 7) * (nwg >> 3) + (lid >> 3);
  const int z = wid & 1, w2 = wid >> 1;
  const int by = w2 % gy, bx = w2 / gy;
  if (z == 0)
    gemm_tile<EPI0, true, false>(Ah, Al, B0h, B0l, bias0, R0h, R0l, nullptr, C0h, C0l,
                                 nullptr, 0x7fffffff, bx, by, N, K, K, 0, As, Bs);
  else
    gemm_tile<EPI1, false, false>(A1, nullptr, B1, nullptr, bias1, R1, nullptr, nullptr, C1, nullptr,
                                  nullptr, 0x7fffffff, bx, by, N, K, K, 0, As, Bs);
}

// ================= gate: latent = sum of 4 split-K partials + bias; logits; top-2 ===============
__global__ void gate_logits(const float* __restrict__ P, size_t pstr,
                            const float* __restrict__ bfv, const float* __restrict__ wg,
                            bf16* __restrict__ latB, int* __restrict__ tokE,
                            float2* __restrict__ tokG) {
  __shared__ float wgs[8 * 512];   // [e][k]
  __shared__ float bfs[512];
  const int tid = threadIdx.x;
  for (int i = tid; i < 4096; i += 256) wgs[(i & 7) * 512 + (i >> 3)] = wg[i];
  for (int i = tid; i < 512; i += 256) bfs[i] = bfv[i];
  __syncthreads();
  const int lane = tid & 63, wv = tid >> 6;
#pragma unroll 1
  for (int tt = 0; tt < 4; ++tt) {
    const int t = blockIdx.x * 16 + wv * 4 + tt;
    float le[8] = {0.f, 0.f, 0.f, 0.f, 0.f, 0.f, 0.f, 0.f};
#pragma unroll
    for (int j = 0; j < 8; ++j) {
      const int k = lane + 64 * j;
      const size_t idx = (size_t)t * 512 + k;
      const float lv = P[idx] + P[pstr + idx] + P[2 * pstr + idx] + P[3 * pstr + idx] + bfs[k];
      latB[idx] = f2bf(lv);
#pragma unroll
      for (int e = 0; e < 8; ++e) le[e] = fmaf(lv, wgs[e * 512 + k], le[e]);
    }
#pragma unroll
    for (int e = 0; e < 8; ++e) {
#pragma unroll
      for (int d = 32; d > 0; d >>= 1) le[e] += __shfl_down(le[e], d);
    }
    if (lane == 0) {
      int i1 = 0; float v1 = le[0];
#pragma unroll
      for (int e = 1; e < 8; ++e) if (le[e] > v1) { v1 = le[e]; i1 = e; }
      int i2 = -1; float v2 = -3.4e38f;
#pragma unroll
      for (int e = 0; e < 8; ++e) if (e != i1 && le[e] > v2) { v2 = le[e]; i2 = e; }
      const float e2 = expf(v2 - v1);
      const float inv = 1.f / (1.f + e2);
      tokE[t] = i1 | (i2 << 8);
      tokG[t] = make_float2(inv, e2 * inv);
    }
  }
}

// ================= deterministic compaction: per-expert token lists + slots ===============
__global__ void gate_compact(const int* __restrict__ tokE, int* __restrict__ perm,
                             int* __restrict__ cnt, int* __restrict__ slot1,
                             int* __restrict__ slot2) {
  const int e = blockIdx.x;
  __shared__ int wsum[16];
  __shared__ int sbase;
  if (threadIdx.x == 0) sbase = 0;
  __syncthreads();
  const int lane = threadIdx.x & 63, wv = threadIdx.x >> 6;
  for (int c0 = 0; c0 < 4096; c0 += 1024) {
    const int t = c0 + threadIdx.x;
    const int te = tokE[t];
    const int which = ((te & 255) == e) ? 0 : ((((te >> 8) & 255) == e) ? 1 : -1);
    const unsigned long long m = __ballot(which >= 0);
    if (lane == 0) wsum[wv] = __popcll(m);
    __syncthreads();
    int off = sbase;
    for (int w = 0; w < wv; ++w) off += wsum[w];
    if (which >= 0) {
      const int slot = off + __popcll(m & ((1ull << lane) - 1ull));
      perm[e * CAP + slot] = t;
      if (which == 0) slot1[t] = slot; else slot2[t] = slot;
    }
    __syncthreads();
    if (threadIdx.x == 0) {
      int s = 0;
#pragma unroll
      for (int w = 0; w < 16; ++w) s += wsum[w];
      sbase += s;
    }
    __syncthreads();
  }
  if (threadIdx.x == 0) cnt[e] = sbase;
}

// ================= combine ===============
__global__ void combine_out(const bf16* __restrict__ He, const float* __restrict__ Wf,
                            const float* __restrict__ Bf, const int* __restrict__ tokE,
                            const float2* __restrict__ tokG, const int* __restrict__ slot1,
                            const int* __restrict__ slot2, float* __restrict__ out) {
  const int b = blockIdx.x * 4 + (threadIdx.x >> 6);
  const int lane = threadIdx.x & 63;
  const int te = tokE[b];
  const float2 gg = tokG[b];
  const int ee[2] = {te & 255, (te >> 8) & 255};
  const int sl[2] = {slot1[b], slot2[b]};
  const float gv[2] = {gg.x, gg.y};
  float y[19];
#pragma unroll
  for (int o = 0; o < 19; ++o) y[o] = 0.f;
#pragma unroll
  for (int t = 0; t < 2; ++t) {
    const bf16* h = He + ((size_t)ee[t] * CAP + sl[t]) * 512;
    float part[19];
#pragma unroll
    for (int o = 0; o < 19; ++o) part[o] = 0.f;
    for (int k = lane; k < 512; k += 64) {
      const float hv = bf2f(h[k]);
      const float* w = Wf + ((size_t)ee[t] * 512 + k) * 19;
#pragma unroll
      for (int o = 0; o < 19; ++o) part[o] = fmaf(hv, w[o], part[o]);
    }
#pragma unroll
    for (int o = 0; o < 19; ++o) y[o] = fmaf(gv[t], part[o], y[o]);
  }
#pragma unroll
  for (int o = 0; o < 19; ++o) {
#pragma unroll
    for (int d = 32; d > 0; d >>= 1) y[o] += __shfl_down(y[o], d);
  }
  if (lane == 0) {
#pragma unroll
    for (int o = 0; o < 19; ++o) {
      float v = y[o] + gg.x * Bf[ee[0] * 19 + o] + gg.y * Bf[ee[1] * 19 + o];
      if (v == 0.f) v = 2.2204460492503131e-16f;
      out[(size_t)b * 20 + o] = v;
    }
  }
}

// ================= value head ===============
__global__ void value_out(const bf16* __restrict__ Hv, const float* __restrict__ Wf,
                          const float* __restrict__ Bf, float* __restrict__ out) {
  const int b = blockIdx.x * 4 + (threadIdx.x >> 6);
  const int lane = threadIdx.x & 63;
  const bf16* h = Hv + (size_t)b * 1024;
  float s = 0.f;
  for (int k = lane; k < 1024; k += 64) s = fmaf(bf2f(h[k]), Wf[k], s);
#pragma unroll
  for (int d = 32; d > 0; d >>= 1) s += __shfl_down(s, d);
  if (lane == 0) out[(size_t)b * 20 + 19] = s + Bf[0];
}

// ================= host =================
extern "C" void kernel_launch(void* const* d_in, const int* in_sizes, int n_in,
                              void* d_out, int out_size, void* d_ws, size_t ws_size,
                              hipStream_t stream) {
  (void)in_sizes; (void)n_in; (void)out_size; (void)ws_size;
  const int Btok = 4096;

  const float* obs   = (const float*)d_in[0];
  const float* encW1 = (const float*)d_in[1];
  const float* encB1 = (const float*)d_in[2];
  const float* encW2 = (const float*)d_in[3];
  const float* encB2 = (const float*)d_in[4];
  const float* encWf = (const float*)d_in[5];
  const float* encBf = (const float*)d_in[6];
  const float* expW1 = (const float*)d_in[7];
  const float* expB1 = (const float*)d_in[8];
  const float* expW2 = (const float*)d_in[9];
  const float* expB2 = (const float*)d_in[10];
  const float* expWf = (const float*)d_in[11];
  const float* expBf = (const float*)d_in[12];
  const float* valW1 = (const float*)d_in[13];
  const float* valB1 = (const float*)d_in[14];
  const float* valW2 = (const float*)d_in[15];
  const float* valB2 = (const float*)d_in[16];
  const float* valWf = (const float*)d_in[17];
  const float* valBf = (const float*)d_in[18];
  const float* wgate = (const float*)d_in[19];

  char* p = (char*)d_ws;
  auto alloc = [&](size_t bytes) -> char* {
    char* r = p; p += (bytes + 255) & ~(size_t)255; return r;
  };
  // weights (bf16, transposed [N][K])
  bf16* encW1tH = (bf16*)alloc((size_t)3 * 1024 * 1024 * 2);
  bf16* encW1tL = (bf16*)alloc((size_t)3 * 1024 * 1024 * 2);
  bf16* encW2tH = (bf16*)alloc((size_t)3 * 1024 * 1024 * 2);
  bf16* encW2tL = (bf16*)alloc((size_t)3 * 1024 * 1024 * 2);
  bf16* encWftH = (bf16*)alloc((size_t)512 * 1024 * 2);
  bf16* encWftL = (bf16*)alloc((size_t)512 * 1024 * 2);
  bf16* valW1t  = (bf16*)alloc((size_t)3 * 1024 * 1024 * 2);
  bf16* valW2t  = (bf16*)alloc((size_t)3 * 1024 * 1024 * 2);
  bf16* expW1t  = (bf16*)alloc((size_t)24 * 512 * 1024 * 2);
  bf16* expW2t  = (bf16*)alloc((size_t)24 * 512 * 1024 * 2);
  // activations
  bf16*  obsH  = (bf16*)alloc((size_t)Btok * 1024 * 2);
  bf16*  tH    = (bf16*)alloc((size_t)Btok * 1024 * 2);
  bf16*  hH    = (bf16*)alloc((size_t)Btok * 1024 * 2);
  bf16*  vT    = (bf16*)alloc((size_t)Btok * 1024 * 2);
  bf16*  vH    = (bf16*)alloc((size_t)Btok * 1024 * 2);
  bf16*  latB  = (bf16*)alloc((size_t)Btok * 512 * 2);
  int*   perm  = (int*)alloc((size_t)8 * CAP * 4);
  int*   cnt   = (int*)alloc(8 * 4);
  int*   tokE  = (int*)alloc((size_t)Btok * 4);
  float2* tokG = (float2*)alloc((size_t)Btok * 8);
  int*   slot1 = (int*)alloc((size_t)Btok * 4);
  int*   slot2 = (int*)alloc((size_t)Btok * 4);
  // He region (32 MiB): also hosts enc-only low/residual temporaries (dead before expert writes)
  char* heR = alloc((size_t)8 * CAP * 512 * 2);
  bf16* He   = (bf16*)heR;
  bf16* tL   = (bf16*)heR;
  bf16* hL   = (bf16*)(heR + (size_t)Btok * 1024 * 2);
  bf16* obsL = (bf16*)(heR + (size_t)2 * Btok * 1024 * 2);
  // Te region (64 MiB): hosts split-K=4 partials P (dead before expert G1 writes Te)
  char* teR = alloc((size_t)8 * CAP * 1024 * 2);
  bf16*  Te = (bf16*)teR;
  float* P  = (float*)teR;
  const size_t pstr = (size_t)Btok * 512;

  const dim3 blk(256);

  // --- conversions (2 dispatches total) ---
  splitv<<<dim3(Btok * 1024 / 4 / 256), blk, 0, stream>>>(obs, obsH, obsL, Btok * 1024 / 4);
  {
    WJobs jb;
    auto set = [&](int i, const float* s, bf16* dh, bf16* dl, int K, int N, int st) {
      jb.j[i] = WJob{s, dh, dl, K, N, st};
    };
    // starts: t1024 slices have 1024 tiles; Wf 512; exp 512/slice
    set(0, encW1, encW1tH, encW1tL, 1024, 1024, 0);        // 3*1024 = 3072
    set(1, encW2, encW2tH, encW2tL, 1024, 1024, 3072);     // 3072
    set(2, encWf, encWftH, encWftL, 1024, 512, 6144);      // 512
    set(3, valW1, valW1t, nullptr, 1024, 1024, 6656);      // 3072
    set(4, valW2, valW2t, nullptr, 1024, 1024, 9728);      // 3072
    set(5, expW1, expW1t, nullptr, 512, 1024, 12800);      // 24*512 = 12288
    set(6, expW2, expW2t, nullptr, 1024, 512, 25088);      // 12288 -> total 37376
    wconv_all<<<dim3(37376), blk, 0, stream>>>(jb);
  }

  // --- encoder (split) + value (plain) fused dual GEMMs ---
  {
    const bf16 *aH = obsH, *aL = obsL, *rH = obsH, *rL = obsL;
    const bf16 *av = obsH, *rv = obsH;
    for (int bi = 0; bi < 3; ++bi) {
      gemm_dual<0, 3><<<dim3(512), blk, 0, stream>>>(
          aH, aL, encW1tH + (size_t)bi * 1024 * 1024, encW1tL + (size_t)bi * 1024 * 1024,
          encB1 + bi * 1024, nullptr, nullptr, tH, tL,
          av, valW1t + (size_t)bi * 1024 * 1024, valB1 + bi * 1024, nullptr, vT,
          Btok, 1024, 1024);
      gemm_dual<1, 4><<<dim3(512), blk, 0, stream>>>(
          tH, tL, encW2tH + (size_t)bi * 1024 * 1024, encW2tL + (size_t)bi * 1024 * 1024,
          encB2 + bi * 1024, rH, rL, hH, hL,
          vT, valW2t + (size_t)bi * 1024 * 1024, valB2 + bi * 1024, rv, vH,
          Btok, 1024, 1024);
      aH = hH; aL = hL; rH = hH; rL = hL;
      av = vH; rv = vH;
    }
  }

  // --- final enc GEMM: split-K=4 -> f32 partials ---
  gemm_bt<6, true, false, true><<<dim3(512), blk, 0, stream>>>(
      hH, hL, 0, encWftH, encWftL, 0, nullptr, 0, nullptr, 0,
      P, nullptr, nullptr, pstr, nullptr, nullptr,
      Btok, 512, 256, 1024);

  // --- gating ---
  gate_logits<<<dim3(256), blk, 0, stream>>>(P, pstr, encBf, wgate, latB, tokE, tokG);
  gate_compact<<<dim3(8), dim3(1024), 0, stream>>>(tokE, perm, cnt, slot1, slot2);

  // --- experts (sparse) ---
  {
    const size_t sW1 = (size_t)512 * 1024, sW2 = (size_t)1024 * 512;
    const size_t sTe = (size_t)CAP * 1024, sHe = (size_t)CAP * 512;
    for (int bi = 0; bi < 3; ++bi) {
      if (bi == 0) {
        gemm_bt<3, false, true, false><<<dim3(2048), blk, 0, stream>>>(
            latB, nullptr, 0, expW1t + bi * sW1, nullptr, 3 * sW1,
            expB1 + bi * 1024, 3 * 1024, nullptr, 0, nullptr, Te, nullptr, sTe,
            perm, cnt, CAP, 1024, 512, 512);
        gemm_bt<5, false, false, false><<<dim3(1024), blk, 0, stream>>>(
            Te, nullptr, sTe, expW2t + bi * sW2, nullptr, 3 * sW2,
            expB2 + bi * 512, 3 * 512, latB, 0, nullptr, He, nullptr, sHe,
            perm, cnt, CAP, 512, 1024, 1024);
      } else {
        gemm_bt<3, false, false, false><<<dim3(2048), blk, 0, stream>>>(
            He, nullptr, sHe, expW1t + bi * sW1, nullptr, 3 * sW1,
            expB1 + bi * 1024, 3 * 1024, nullptr, 0, nullptr, Te, nullptr, sTe,
            perm, cnt, CAP, 1024, 512, 512);
        gemm_bt<4, false, false, false><<<dim3(1024), blk, 0, stream>>>(
            Te, nullptr, sTe, expW2t + bi * sW2, nullptr, 3 * sW2,
            expB2 + bi * 512, 3 * 512, He, sHe, nullptr, He, nullptr, sHe,
            perm, cnt, CAP, 512, 1024, 1024);
      }
    }
  }
  combine_out<<<dim3(1024), blk, 0, stream>>>(He, expWf, expBf, tokE, tokG, slot1, slot2,
                                              (float*)d_out);
  value_out<<<dim3(1024), blk, 0, stream>>>(vH, valWf, valBf, (float*)d_out);
}

// Round 6
// 721.505 us; speedup vs baseline: 1.1466x; 1.1466x over previous
//
#include <hip/hip_runtime.h>
#include <hip/hip_bf16.h>
#include <stdint.h>
#include <stddef.h>

typedef __hip_bfloat16 bf16;
typedef __attribute__((ext_vector_type(8))) short short8;
typedef __attribute__((ext_vector_type(4))) float f32x4;

#define GLDS16(g, l) __builtin_amdgcn_global_load_lds( \
    (const __attribute__((address_space(1))) void*)(g), \
    (__attribute__((address_space(3))) void*)(l), 16, 0, 0)

__device__ __forceinline__ float bf2f(bf16 x) { return __bfloat162float(x); }
__device__ __forceinline__ bf16  f2bf(float x) { return __float2bfloat16(x); }

constexpr int CAP = 4096;

// ================= merged weight convert+transpose (all weights, one dispatch) ===============
struct WJob { const float* src; bf16* dhi; bf16* dlo; int K, N, start; };
struct WJobs { WJob j[7]; };

__global__ void wconv_all(WJobs jobs) {
  __shared__ float tile[32][33];
  const int bid = blockIdx.x;
  int ji = 0;
#pragma unroll
  for (int t = 1; t < 7; ++t) if (bid >= jobs.j[t].start) ji = t;
  const WJob J = jobs.j[ji];
  const int K = J.K, N = J.N;
  const int nx = N >> 5, tps = nx * (K >> 5);
  const int local = bid - J.start;
  const int z = local / tps, rem = local % tps;
  const int n0 = (rem % nx) * 32, k0 = (rem / nx) * 32;
  const size_t zoff = (size_t)z * K * N;
  const float* s = J.src + zoff;
  const int tx = threadIdx.x & 31, ty = threadIdx.x >> 5;
#pragma unroll
  for (int i = 0; i < 32; i += 8)
    tile[ty + i][tx] = s[(size_t)(k0 + ty + i) * N + (n0 + tx)];
  __syncthreads();
  const bool split = (J.dlo != nullptr);
#pragma unroll
  for (int i = 0; i < 32; i += 8) {
    const float v = tile[tx][ty + i];
    const size_t o = zoff + (size_t)(n0 + ty + i) * K + (k0 + tx);
    const bf16 h = f2bf(v);
    J.dhi[o] = h;
    if (split) J.dlo[o] = f2bf(v - bf2f(h));
  }
}

// ================= elementwise f32 -> bf16 hi/lo split =================
__global__ void splitv(const float* __restrict__ x, bf16* __restrict__ hi,
                       bf16* __restrict__ lo, int n4) {
  const int i = blockIdx.x * 256 + threadIdx.x;
  if (i >= n4) return;
  const float4 v = ((const float4*)x)[i];
  const float f[4] = {v.x, v.y, v.z, v.w};
#pragma unroll
  for (int j = 0; j < 4; ++j) {
    const bf16 h = f2bf(f[j]);
    hi[i * 4 + j] = h;
    lo[i * 4 + j] = f2bf(f[j] - bf2f(h));
  }
}

// ================= core 128x128 tile GEMM body, BK=64 =================
// EPI: 0 relu -> (Ch,Cl)            1 +bias +Rh+Rl -> (Ch,Cl)
//      3 relu -> Ch                 4 +bias +Rb -> Ch
//      5 +bias +Rb(perm-gathered rows) -> Ch
//      6 raw f32 partial -> Cf (split-K, no bias)
template<int EPI, bool SPLIT, bool GATHER>
__device__ __forceinline__ void gemm_tile(
    const bf16* __restrict__ Ah, const bf16* __restrict__ Al,
    const bf16* __restrict__ Bh, const bf16* __restrict__ Bl,
    const float* __restrict__ bias,
    const bf16* __restrict__ Rb, const bf16* __restrict__ Rl2,
    float* __restrict__ Cf, bf16* __restrict__ Ch, bf16* __restrict__ Cl,
    const int* __restrict__ permz, int cE,
    int bx, int by, int N, int K, int lda, int kbase,
    bf16* As, bf16* Bs) {
  const int tid = threadIdx.x, lane = tid & 63, wave = tid >> 6;
  const int wr = wave >> 1, wc = wave & 1;
  const int fr = lane & 15, q = lane >> 4, fq = q << 2;

  int arow[4], brow[4];
#pragma unroll
  for (int i = 0; i < 4; ++i) {
    const int r = (i * 256 + tid) >> 3;
    const int slot = bx * 128 + r;
    arow[i] = GATHER ? ((slot < cE) ? permz[slot] : 0) : slot;
    brow[i] = by * 128 + r;
  }

  f32x4 acc[4][4];
#pragma unroll
  for (int m = 0; m < 4; ++m)
#pragma unroll
    for (int n = 0; n < 4; ++n) {
      acc[m][n][0] = 0.f; acc[m][n][1] = 0.f; acc[m][n][2] = 0.f; acc[m][n][3] = 0.f;
    }

  const int nk = K >> 6;
  for (int kt = 0; kt < nk; ++kt) {
    const int k0 = kbase + (kt << 6);
#pragma unroll
    for (int i = 0; i < 4; ++i) {
      const int ci = i * 256 + tid;
      const int r = ci >> 3, pch = ci & 7;
      const int c = pch ^ (r & 7);                  // inverse-swizzled global chunk
      const size_t ga = (size_t)arow[i] * lda + k0 + c * 8;
      const size_t gb = (size_t)brow[i] * lda + k0 + c * 8;
      GLDS16(Ah + ga, As + ci * 8);
      GLDS16(Bh + gb, Bs + ci * 8);
      if (SPLIT) {
        GLDS16(Al + ga, As + 8192 + ci * 8);
        GLDS16(Bl + gb, Bs + 8192 + ci * 8);
      }
    }
    __syncthreads();

#pragma unroll
    for (int kk = 0; kk < 2; ++kk) {
      auto LD = [&](const bf16* base, int r) -> short8 {
        const int c = ((kk << 2) + q) ^ (r & 7);   // swizzled fragment read
        return *(const short8*)(base + r * 64 + c * 8);
      };
      short8 a0[4], b0[4];
#pragma unroll
      for (int m = 0; m < 4; ++m) a0[m] = LD(As, wr * 64 + m * 16 + fr);
#pragma unroll
      for (int n = 0; n < 4; ++n) b0[n] = LD(Bs, wc * 64 + n * 16 + fr);
      if (SPLIT) {
        short8 a1[4], b1[4];
#pragma unroll
        for (int m = 0; m < 4; ++m) a1[m] = LD(As + 8192, wr * 64 + m * 16 + fr);
#pragma unroll
        for (int n = 0; n < 4; ++n) b1[n] = LD(Bs + 8192, wc * 64 + n * 16 + fr);
#pragma unroll
        for (int m = 0; m < 4; ++m)
#pragma unroll
          for (int n = 0; n < 4; ++n) {
            acc[m][n] = __builtin_amdgcn_mfma_f32_16x16x32_bf16(a1[m], b0[n], acc[m][n], 0, 0, 0);
            acc[m][n] = __builtin_amdgcn_mfma_f32_16x16x32_bf16(a0[m], b1[n], acc[m][n], 0, 0, 0);
          }
      }
#pragma unroll
      for (int m = 0; m < 4; ++m)
#pragma unroll
        for (int n = 0; n < 4; ++n)
          acc[m][n] = __builtin_amdgcn_mfma_f32_16x16x32_bf16(a0[m], b0[n], acc[m][n], 0, 0, 0);
    }
    __syncthreads();
  }

#pragma unroll
  for (int n = 0; n < 4; ++n) {
    const int col = by * 128 + wc * 64 + n * 16 + fr;
    const float bv = (EPI == 6) ? 0.f : bias[col];
#pragma unroll
    for (int m = 0; m < 4; ++m) {
      const int row0 = bx * 128 + wr * 64 + m * 16 + fq;
#pragma unroll
      for (int r = 0; r < 4; ++r) {
        const int rowi = row0 + r;
        const size_t o = (size_t)rowi * N + col;
        float v = acc[m][n][r] + bv;
        if (EPI == 0 || EPI == 3) v = fmaxf(v, 0.f);
        if (EPI == 1) v += bf2f(Rb[o]) + bf2f(Rl2[o]);
        if (EPI == 4) v += bf2f(Rb[o]);
        if (EPI == 5) {
          const int rr = (rowi < cE) ? permz[rowi] : 0;
          v += bf2f(Rb[(size_t)rr * N + col]);
        }
        if (EPI == 6) {
          Cf[o] = v;
        } else {
          const bf16 h = f2bf(v);
          Ch[o] = h;
          if (EPI == 0 || EPI == 1) Cl[o] = f2bf(v - bf2f(h));
        }
      }
    }
  }
}

// ================= single GEMM (experts / split-K final) ===============
template<int EPI, bool SPLIT, bool GATHER, bool SPLITK>
__global__ __launch_bounds__(256, 2)
void gemm_bt(const bf16* __restrict__ Ah, const bf16* __restrict__ Al, size_t aSz,
             const bf16* __restrict__ Bh, const bf16* __restrict__ Bl, size_t bSz,
             const float* __restrict__ bias, size_t biasSz,
             const void* __restrict__ R, size_t rSz,
             float* __restrict__ Cf, bf16* __restrict__ Ch, bf16* __restrict__ Cl, size_t cSz,
             const int* __restrict__ perm, const int* __restrict__ cnt,
             int M, int N, int K, int lda) {
  __shared__ __align__(16) bf16 As[(SPLIT ? 2 : 1) * 8192];
  __shared__ __align__(16) bf16 Bs[(SPLIT ? 2 : 1) * 8192];
  const int gx = M >> 7, gy = N >> 7, nwg = gridDim.x, lid = blockIdx.x;
  const int wid = (lid & 7) * (nwg >> 3) + (lid >> 3);
  const int by = wid % gy, bx = (wid / gy) % gx, bz = wid / (gy * gx);

  int cE = 0x7fffffff;
  if (cnt) { cE = cnt[bz]; if (bx * 128 >= cE) return; }

  Ah += (size_t)bz * aSz;
  Bh += (size_t)bz * bSz;
  if (SPLIT) { Al += (size_t)bz * aSz; Bl += (size_t)bz * bSz; }
  if (bias) bias += (size_t)bz * biasSz;
  const bf16* Rb = (const bf16*)R;
  if (EPI == 4) Rb += (size_t)bz * rSz;
  if (EPI == 6) Cf += (size_t)bz * cSz; else Ch += (size_t)bz * cSz;
  const int* permz = perm ? (perm + (size_t)bz * CAP) : nullptr;
  const int kbase = SPLITK ? bz * K : 0;

  gemm_tile<EPI, SPLIT, GATHER>(Ah, Al, Bh, Bl, bias, Rb, nullptr, Cf, Ch, Cl,
                                permz, cE, bx, by, N, K, lda, kbase, As, Bs);
}

// ================= dual GEMM: balanced pairing ===============
// lid in [0,512): z = lid>>8 (0 enc/split, 1 val/plain), tile = lid&255.
// By XCD round-robin dispatch, lid and lid+256 co-reside on one CU -> each CU
// gets exactly one split (3x work) + one plain (1x work) block.
template<int EPI0, int EPI1>
__global__ __launch_bounds__(256, 2)
void gemm_dual(const bf16* __restrict__ Ah, const bf16* __restrict__ Al,
               const bf16* __restrict__ B0h, const bf16* __restrict__ B0l,
               const float* __restrict__ bias0,
               const bf16* __restrict__ R0h, const bf16* __restrict__ R0l,
               bf16* __restrict__ C0h, bf16* __restrict__ C0l,
               const bf16* __restrict__ A1, const bf16* __restrict__ B1,
               const float* __restrict__ bias1, const bf16* __restrict__ R1,
               bf16* __restrict__ C1,
               int M, int N, int K) {
  __shared__ __align__(16) bf16 As[2 * 8192];
  __shared__ __align__(16) bf16 Bs[2 * 8192];
  const int gy = N >> 7, lid = blockIdx.x;
  const int z = lid >> 8, t = lid & 255;
  const int wid = (t & 7) * 32 + (t >> 3);        // XCD-contiguous swizzle within half
  const int by = wid % gy, bx = wid / gy;
  if (z == 0)
    gemm_tile<EPI0, true, false>(Ah, Al, B0h, B0l, bias0, R0h, R0l, nullptr, C0h, C0l,
                                 nullptr, 0x7fffffff, bx, by, N, K, K, 0, As, Bs);
  else
    gemm_tile<EPI1, false, false>(A1, nullptr, B1, nullptr, bias1, R1, nullptr, nullptr, C1, nullptr,
                                  nullptr, 0x7fffffff, bx, by, N, K, K, 0, As, Bs);
}

// ================= gate: latent = sum of 4 split-K partials + bias; logits; top-2 ===============
__global__ void gate_logits(const float* __restrict__ P, size_t pstr,
                            const float* __restrict__ bfv, const float* __restrict__ wg,
                            bf16* __restrict__ latB, int* __restrict__ tokE,
                            float2* __restrict__ tokG) {
  __shared__ float wgs[8 * 512];   // [e][k]
  __shared__ float bfs[512];
  const int tid = threadIdx.x;
  for (int i = tid; i < 4096; i += 256) wgs[(i & 7) * 512 + (i >> 3)] = wg[i];
  for (int i = tid; i < 512; i += 256) bfs[i] = bfv[i];
  __syncthreads();
  const int lane = tid & 63, wv = tid >> 6;
#pragma unroll 1
  for (int tt = 0; tt < 4; ++tt) {
    const int t = blockIdx.x * 16 + wv * 4 + tt;
    float le[8] = {0.f, 0.f, 0.f, 0.f, 0.f, 0.f, 0.f, 0.f};
#pragma unroll
    for (int j = 0; j < 8; ++j) {
      const int k = lane + 64 * j;
      const size_t idx = (size_t)t * 512 + k;
      const float lv = P[idx] + P[pstr + idx] + P[2 * pstr + idx] + P[3 * pstr + idx] + bfs[k];
      latB[idx] = f2bf(lv);
#pragma unroll
      for (int e = 0; e < 8; ++e) le[e] = fmaf(lv, wgs[e * 512 + k], le[e]);
    }
#pragma unroll
    for (int e = 0; e < 8; ++e) {
#pragma unroll
      for (int d = 32; d > 0; d >>= 1) le[e] += __shfl_down(le[e], d);
    }
    if (lane == 0) {
      int i1 = 0; float v1 = le[0];
#pragma unroll
      for (int e = 1; e < 8; ++e) if (le[e] > v1) { v1 = le[e]; i1 = e; }
      int i2 = -1; float v2 = -3.4e38f;
#pragma unroll
      for (int e = 0; e < 8; ++e) if (e != i1 && le[e] > v2) { v2 = le[e]; i2 = e; }
      const float e2 = expf(v2 - v1);
      const float inv = 1.f / (1.f + e2);
      tokE[t] = i1 | (i2 << 8);
      tokG[t] = make_float2(inv, e2 * inv);
    }
  }
}

// ================= deterministic compaction: per-expert token lists + slots ===============
__global__ void gate_compact(const int* __restrict__ tokE, int* __restrict__ perm,
                             int* __restrict__ cnt, int* __restrict__ slot1,
                             int* __restrict__ slot2) {
  const int e = blockIdx.x;
  __shared__ int wsum[16];
  __shared__ int sbase;
  if (threadIdx.x == 0) sbase = 0;
  __syncthreads();
  const int lane = threadIdx.x & 63, wv = threadIdx.x >> 6;
  for (int c0 = 0; c0 < 4096; c0 += 1024) {
    const int t = c0 + threadIdx.x;
    const int te = tokE[t];
    const int which = ((te & 255) == e) ? 0 : ((((te >> 8) & 255) == e) ? 1 : -1);
    const unsigned long long m = __ballot(which >= 0);
    if (lane == 0) wsum[wv] = __popcll(m);
    __syncthreads();
    int off = sbase;
    for (int w = 0; w < wv; ++w) off += wsum[w];
    if (which >= 0) {
      const int slot = off + __popcll(m & ((1ull << lane) - 1ull));
      perm[e * CAP + slot] = t;
      if (which == 0) slot1[t] = slot; else slot2[t] = slot;
    }
    __syncthreads();
    if (threadIdx.x == 0) {
      int s = 0;
#pragma unroll
      for (int w = 0; w < 16; ++w) s += wsum[w];
      sbase += s;
    }
    __syncthreads();
  }
  if (threadIdx.x == 0) cnt[e] = sbase;
}

// ================= combine ===============
__global__ void combine_out(const bf16* __restrict__ He, const float* __restrict__ Wf,
                            const float* __restrict__ Bf, const int* __restrict__ tokE,
                            const float2* __restrict__ tokG, const int* __restrict__ slot1,
                            const int* __restrict__ slot2, float* __restrict__ out) {
  const int b = blockIdx.x * 4 + (threadIdx.x >> 6);
  const int lane = threadIdx.x & 63;
  const int te = tokE[b];
  const float2 gg = tokG[b];
  const int ee[2] = {te & 255, (te >> 8) & 255};
  const int sl[2] = {slot1[b], slot2[b]};
  const float gv[2] = {gg.x, gg.y};
  float y[19];
#pragma unroll
  for (int o = 0; o < 19; ++o) y[o] = 0.f;
#pragma unroll
  for (int t = 0; t < 2; ++t) {
    const bf16* h = He + ((size_t)ee[t] * CAP + sl[t]) * 512;
    float part[19];
#pragma unroll
    for (int o = 0; o < 19; ++o) part[o] = 0.f;
    for (int k = lane; k < 512; k += 64) {
      const float hv = bf2f(h[k]);
      const float* w = Wf + ((size_t)ee[t] * 512 + k) * 19;
#pragma unroll
      for (int o = 0; o < 19; ++o) part[o] = fmaf(hv, w[o], part[o]);
    }
#pragma unroll
    for (int o = 0; o < 19; ++o) y[o] = fmaf(gv[t], part[o], y[o]);
  }
#pragma unroll
  for (int o = 0; o < 19; ++o) {
#pragma unroll
    for (int d = 32; d > 0; d >>= 1) y[o] += __shfl_down(y[o], d);
  }
  if (lane == 0) {
#pragma unroll
    for (int o = 0; o < 19; ++o) {
      float v = y[o] + gg.x * Bf[ee[0] * 19 + o] + gg.y * Bf[ee[1] * 19 + o];
      if (v == 0.f) v = 2.2204460492503131e-16f;
      out[(size_t)b * 20 + o] = v;
    }
  }
}

// ================= value head ===============
__global__ void value_out(const bf16* __restrict__ Hv, const float* __restrict__ Wf,
                          const float* __restrict__ Bf, float* __restrict__ out) {
  const int b = blockIdx.x * 4 + (threadIdx.x >> 6);
  const int lane = threadIdx.x & 63;
  const bf16* h = Hv + (size_t)b * 1024;
  float s = 0.f;
  for (int k = lane; k < 1024; k += 64) s = fmaf(bf2f(h[k]), Wf[k], s);
#pragma unroll
  for (int d = 32; d > 0; d >>= 1) s += __shfl_down(s, d);
  if (lane == 0) out[(size_t)b * 20 + 19] = s + Bf[0];
}

// ================= host =================
extern "C" void kernel_launch(void* const* d_in, const int* in_sizes, int n_in,
                              void* d_out, int out_size, void* d_ws, size_t ws_size,
                              hipStream_t stream) {
  (void)in_sizes; (void)n_in; (void)out_size; (void)ws_size;
  const int Btok = 4096;

  const float* obs   = (const float*)d_in[0];
  const float* encW1 = (const float*)d_in[1];
  const float* encB1 = (const float*)d_in[2];
  const float* encW2 = (const float*)d_in[3];
  const float* encB2 = (const float*)d_in[4];
  const float* encWf = (const float*)d_in[5];
  const float* encBf = (const float*)d_in[6];
  const float* expW1 = (const float*)d_in[7];
  const float* expB1 = (const float*)d_in[8];
  const float* expW2 = (const float*)d_in[9];
  const float* expB2 = (const float*)d_in[10];
  const float* expWf = (const float*)d_in[11];
  const float* expBf = (const float*)d_in[12];
  const float* valW1 = (const float*)d_in[13];
  const float* valB1 = (const float*)d_in[14];
  const float* valW2 = (const float*)d_in[15];
  const float* valB2 = (const float*)d_in[16];
  const float* valWf = (const float*)d_in[17];
  const float* valBf = (const float*)d_in[18];
  const float* wgate = (const float*)d_in[19];

  char* p = (char*)d_ws;
  auto alloc = [&](size_t bytes) -> char* {
    char* r = p; p += (bytes + 255) & ~(size_t)255; return r;
  };
  // weights (bf16, transposed [N][K])
  bf16* encW1tH = (bf16*)alloc((size_t)3 * 1024 * 1024 * 2);
  bf16* encW1tL = (bf16*)alloc((size_t)3 * 1024 * 1024 * 2);
  bf16* encW2tH = (bf16*)alloc((size_t)3 * 1024 * 1024 * 2);
  bf16* encW2tL = (bf16*)alloc((size_t)3 * 1024 * 1024 * 2);
  bf16* encWftH = (bf16*)alloc((size_t)512 * 1024 * 2);
  bf16* encWftL = (bf16*)alloc((size_t)512 * 1024 * 2);
  bf16* valW1t  = (bf16*)alloc((size_t)3 * 1024 * 1024 * 2);
  bf16* valW2t  = (bf16*)alloc((size_t)3 * 1024 * 1024 * 2);
  bf16* expW1t  = (bf16*)alloc((size_t)24 * 512 * 1024 * 2);
  bf16* expW2t  = (bf16*)alloc((size_t)24 * 512 * 1024 * 2);
  // activations
  bf16*  obsH  = (bf16*)alloc((size_t)Btok * 1024 * 2);
  bf16*  tH    = (bf16*)alloc((size_t)Btok * 1024 * 2);
  bf16*  hH    = (bf16*)alloc((size_t)Btok * 1024 * 2);
  bf16*  vT    = (bf16*)alloc((size_t)Btok * 1024 * 2);
  bf16*  vH    = (bf16*)alloc((size_t)Btok * 1024 * 2);
  bf16*  latB  = (bf16*)alloc((size_t)Btok * 512 * 2);
  int*   perm  = (int*)alloc((size_t)8 * CAP * 4);
  int*   cnt   = (int*)alloc(8 * 4);
  int*   tokE  = (int*)alloc((size_t)Btok * 4);
  float2* tokG = (float2*)alloc((size_t)Btok * 8);
  int*   slot1 = (int*)alloc((size_t)Btok * 4);
  int*   slot2 = (int*)alloc((size_t)Btok * 4);
  // He region (32 MiB): also hosts enc-only low/residual temporaries (dead before expert writes)
  char* heR = alloc((size_t)8 * CAP * 512 * 2);
  bf16* He   = (bf16*)heR;
  bf16* tL   = (bf16*)heR;
  bf16* hL   = (bf16*)(heR + (size_t)Btok * 1024 * 2);
  bf16* obsL = (bf16*)(heR + (size_t)2 * Btok * 1024 * 2);
  // Te region (64 MiB): hosts split-K=4 partials P (dead before expert G1 writes Te)
  char* teR = alloc((size_t)8 * CAP * 1024 * 2);
  bf16*  Te = (bf16*)teR;
  float* P  = (float*)teR;
  const size_t pstr = (size_t)Btok * 512;

  const dim3 blk(256);

  // --- conversions (2 dispatches total) ---
  splitv<<<dim3(Btok * 1024 / 4 / 256), blk, 0, stream>>>(obs, obsH, obsL, Btok * 1024 / 4);
  {
    WJobs jb;
    auto set = [&](int i, const float* s, bf16* dh, bf16* dl, int K, int N, int st) {
      jb.j[i] = WJob{s, dh, dl, K, N, st};
    };
    set(0, encW1, encW1tH, encW1tL, 1024, 1024, 0);        // 3072
    set(1, encW2, encW2tH, encW2tL, 1024, 1024, 3072);     // 3072
    set(2, encWf, encWftH, encWftL, 1024, 512, 6144);      // 512
    set(3, valW1, valW1t, nullptr, 1024, 1024, 6656);      // 3072
    set(4, valW2, valW2t, nullptr, 1024, 1024, 9728);      // 3072
    set(5, expW1, expW1t, nullptr, 512, 1024, 12800);      // 12288
    set(6, expW2, expW2t, nullptr, 1024, 512, 25088);      // 12288 -> 37376
    wconv_all<<<dim3(37376), blk, 0, stream>>>(jb);
  }

  // --- encoder (split) + value (plain) fused dual GEMMs, balanced pairing ---
  {
    const bf16 *aH = obsH, *aL = obsL, *rH = obsH, *rL = obsL;
    const bf16 *av = obsH, *rv = obsH;
    for (int bi = 0; bi < 3; ++bi) {
      gemm_dual<0, 3><<<dim3(512), blk, 0, stream>>>(
          aH, aL, encW1tH + (size_t)bi * 1024 * 1024, encW1tL + (size_t)bi * 1024 * 1024,
          encB1 + bi * 1024, nullptr, nullptr, tH, tL,
          av, valW1t + (size_t)bi * 1024 * 1024, valB1 + bi * 1024, nullptr, vT,
          Btok, 1024, 1024);
      gemm_dual<1, 4><<<dim3(512), blk, 0, stream>>>(
          tH, tL, encW2tH + (size_t)bi * 1024 * 1024, encW2tL + (size_t)bi * 1024 * 1024,
          encB2 + bi * 1024, rH, rL, hH, hL,
          vT, valW2t + (size_t)bi * 1024 * 1024, valB2 + bi * 1024, rv, vH,
          Btok, 1024, 1024);
      aH = hH; aL = hL; rH = hH; rL = hL;
      av = vH; rv = vH;
    }
  }

  // --- final enc GEMM: split-K=4 -> f32 partials ---
  gemm_bt<6, true, false, true><<<dim3(512), blk, 0, stream>>>(
      hH, hL, 0, encWftH, encWftL, 0, nullptr, 0, nullptr, 0,
      P, nullptr, nullptr, pstr, nullptr, nullptr,
      Btok, 512, 256, 1024);

  // --- gating ---
  gate_logits<<<dim3(256), blk, 0, stream>>>(P, pstr, encBf, wgate, latB, tokE, tokG);
  gate_compact<<<dim3(8), dim3(1024), 0, stream>>>(tokE, perm, cnt, slot1, slot2);

  // --- experts (sparse) ---
  {
    const size_t sW1 = (size_t)512 * 1024, sW2 = (size_t)1024 * 512;
    const size_t sTe = (size_t)CAP * 1024, sHe = (size_t)CAP * 512;
    for (int bi = 0; bi < 3; ++bi) {
      if (bi == 0) {
        gemm_bt<3, false, true, false><<<dim3(2048), blk, 0, stream>>>(
            latB, nullptr, 0, expW1t + bi * sW1, nullptr, 3 * sW1,
            expB1 + bi * 1024, 3 * 1024, nullptr, 0, nullptr, Te, nullptr, sTe,
            perm, cnt, CAP, 1024, 512, 512);
        gemm_bt<5, false, false, false><<<dim3(1024), blk, 0, stream>>>(
            Te, nullptr, sTe, expW2t + bi * sW2, nullptr, 3 * sW2,
            expB2 + bi * 512, 3 * 512, latB, 0, nullptr, He, nullptr, sHe,
            perm, cnt, CAP, 512, 1024, 1024);
      } else {
        gemm_bt<3, false, false, false><<<dim3(2048), blk, 0, stream>>>(
            He, nullptr, sHe, expW1t + bi * sW1, nullptr, 3 * sW1,
            expB1 + bi * 1024, 3 * 1024, nullptr, 0, nullptr, Te, nullptr, sTe,
            perm, cnt, CAP, 1024, 512, 512);
        gemm_bt<4, false, false, false><<<dim3(1024), blk, 0, stream>>>(
            Te, nullptr, sTe, expW2t + bi * sW2, nullptr, 3 * sW2,
            expB2 + bi * 512, 3 * 512, He, sHe, nullptr, He, nullptr, sHe,
            perm, cnt, CAP, 512, 1024, 1024);
      }
    }
  }
  combine_out<<<dim3(1024), blk, 0, stream>>>(He, expWf, expBf, tokE, tokG, slot1, slot2,
                                              (float*)d_out);
  value_out<<<dim3(1024), blk, 0, stream>>>(vH, valWf, valBf, (float*)d_out);
}